// Round 1
// baseline (325.881 us; speedup 1.0000x reference)
//
#include <hip/hip_runtime.h>
#include <stdint.h>

#define N_ROWS 16384
#define DIM    512

typedef float v4f __attribute__((ext_vector_type(4)));
typedef unsigned long long u64;
typedef unsigned char u8;

template <int N> struct IC { static constexpr int value = N; };

// Monotonic float -> sortable u32 key
__device__ __forceinline__ unsigned fkey(float f) {
    unsigned u = __float_as_uint(f);
    return (u & 0x80000000u) ? ~u : (u | 0x80000000u);
}

// Async global->LDS, 16B per lane. LDS dest = wave-uniform base + lane*16.
__device__ __forceinline__ void gload_lds16(const void* g, void* l) {
    __builtin_amdgcn_global_load_lds(
        (const __attribute__((address_space(1))) unsigned int*)g,
        (__attribute__((address_space(3))) unsigned int*)l,
        16, 0, 0);
}

// ---------------- kernel 1: fp32 -> fp8 e4m3 convert (+ table zero-init) ----------------
// HW RNE; x ~ N(0,1), e4m3 max 448 -> no saturation. Validated earlier (absmax 0.0).
__global__ __launch_bounds__(256)
void convert_fp8_kernel(const float* __restrict__ x, unsigned* __restrict__ x8,
                        u64* __restrict__ table) {
    int tid    = blockIdx.x * blockDim.x + threadIdx.x;
    int stride = gridDim.x * blockDim.x;
    if (tid < N_ROWS) table[tid] = 0;
    const float4* x4 = (const float4*)x;
    const int n4 = (N_ROWS * DIM) / 4;
    for (int i = tid; i < n4; i += stride) {
        float4 v = x4[i];
        int b = __builtin_amdgcn_cvt_pk_fp8_f32(v.x, v.y, 0, false);   // bytes 0,1
        b     = __builtin_amdgcn_cvt_pk_fp8_f32(v.z, v.w, b, true);    // bytes 2,3
        x8[i] = (unsigned)b;
    }
}

// ---------------- kernel 2: 256x256-tile fp8 GEMM + fused argmax, 8-wave phase-split ----------------
// r9: port the proven 128^2 kernel to the 256^2 8-wave counted-vmcnt schedule
// (guide T3+T4+T5; the m97-style 2-barrier structure ceilings at ~36-39%).
//  * Triangle fold at 64 tiles/side: 2080 blocks; u=bid>>5 in [0,65), p=bid&31;
//    u<=p -> (63-p,63-u) else (p,u-1). Bijective over {r<=c} (checked).
//  * 512 threads = 8 waves (2 row-halves x 4 col-quarters); per-wave out 128x64;
//    acc[8][4] v4f = 128 VGPR -> 1 block/CU, __launch_bounds__(512,2).
//  * BK=64 fp8, double-buffered: LDS = 2buf x 2half x (128 rows x 64 B) x {A,B}
//    = 64 KB exactly. Staging unit = 8 KB = 1 gload_lds16 per thread; 4 units/tile.
//  * Counted vmcnt: per tile s_waitcnt vmcnt(4) (next tile's 4 units stay in
//    flight across the barrier); vmcnt(0) only at the last tile. Raw s_barrier
//    only -- no __syncthreads (whose vmcnt(0) drain is the measured m97 stall).
//  * Phase split: 2 phases/tile (one per K=32 step): 12x ds_read_b64 ->
//    barrier -> lgkmcnt(0)+sched_barrier(0) -> setprio(1) -> 32 MFMA ->
//    setprio(0) -> barrier. STAGE(t+2) after the last post-MFMA barrier
//    (write-after-read safe: all waves' reads retired before that barrier).
//  * Swizzle for 64-B rows (4 chunks of 16 B): slot = kc ^ ((row>>1)&3) ->
//    exact 2-way bank aliasing per 32-lane phase (free, m136). Pre-swizzled
//    global source + linear LDS dest (rule #21). Reader xor collapses to
//    ((lane15>>1)&3) because rf*16, cf*16, (wc&1)*64 are all = 0 mod 8... mod 4
//    after >>1, so it is lane-only.
//  * MFMA fragment math identical to the proven kernel: lane(l15, q) holds
//    bytes [8q, 8q+8) of the K=32 window; C/D layout col=l15+16cf, row=4*quad+e.
__global__ __launch_bounds__(512, 2)
void argmax_dots_kernel(const u8* __restrict__ xb, u64* __restrict__ table) {
    __shared__ __attribute__((aligned(16))) u8 ldsA[2][2][8192];  // [buf][half][128x64]
    __shared__ __attribute__((aligned(16))) u8 ldsB[2][2][8192];

    const int u = blockIdx.x >> 5;       // [0,65)
    const int p = blockIdx.x & 31;       // [0,32)
    const int rT = (u <= p) ? (63 - p) : p;
    const int cT = (u <= p) ? (63 - u) : (u - 1);

    const int t      = threadIdx.x;      // [0,512)
    const int lane   = t & 63;
    const int wave   = t >> 6;           // [0,8)
    const int lane15 = lane & 15;
    const int quad   = lane >> 4;
    const int wr     = wave >> 2;        // row half   {0,1}
    const int wc     = wave & 3;         // col quarter {0..3}

    const int rowBase = rT * 256;
    const int colBase = cT * 256;

    // ---- staging sources: 1 issue per 8KB unit per thread, pre-swizzled ----
    const int r128 = t >> 2;                       // row within half [0,128)
    const int kcs  = (t & 3) ^ ((r128 >> 1) & 3);  // swizzled source chunk
    const u8* sA0 = xb + (size_t)(rowBase +       r128) * DIM + kcs * 16;
    const u8* sA1 = xb + (size_t)(rowBase + 128 + r128) * DIM + kcs * 16;
    const u8* sB0 = xb + (size_t)(colBase +       r128) * DIM + kcs * 16;
    const u8* sB1 = xb + (size_t)(colBase + 128 + r128) * DIM + kcs * 16;
    const int ldsOff = wave * 1024;                // lane*16 added by HW

#define STAGE(T) do {                                              \
        gload_lds16(sA0 + (T) * 64, &ldsA[(T) & 1][0][ldsOff]);    \
        gload_lds16(sA1 + (T) * 64, &ldsA[(T) & 1][1][ldsOff]);    \
        gload_lds16(sB0 + (T) * 64, &ldsB[(T) & 1][0][ldsOff]);    \
        gload_lds16(sB1 + (T) * 64, &ldsB[(T) & 1][1][ldsOff]);    \
    } while (0)

    // ---- per-lane LDS read offsets ----
    const int rdOff = lane15 * 64 + (quad & 1) * 8;
    int xorK[2];
#pragma unroll
    for (int ks = 0; ks < 2; ++ks)
        xorK[ks] = ((2 * ks + (quad >> 1)) ^ ((lane15 >> 1) & 3)) << 4;
    const int bcOff = (wc & 1) * 4096;   // col-within-half base (64 rows * 64 B)

    v4f acc[8][4];
#pragma unroll
    for (int rf = 0; rf < 8; ++rf)
#pragma unroll
        for (int cf = 0; cf < 4; ++cf) {
            v4f z = {0.f, 0.f, 0.f, 0.f};
            acc[rf][cf] = z;
        }

    STAGE(0);
    STAGE(1);

    auto ktile = [&](auto TC) {
        constexpr int T  = TC.value;
        constexpr int WN = (T < 7) ? 4 : 0;   // counted: next tile's 4 units fly
        asm volatile("s_waitcnt vmcnt(%0)" :: "n"(WN) : "memory");
        __builtin_amdgcn_s_barrier();         // tile T resident for all waves
        const u8* A = &ldsA[T & 1][wr][0];
        const u8* B = &ldsB[T & 1][wc >> 1][0];
#pragma unroll
        for (int ks = 0; ks < 2; ++ks) {
            long a8[8], b8[4];
#pragma unroll
            for (int rf = 0; rf < 8; ++rf)
                a8[rf] = *(const long*)(A + rf * 1024 + rdOff + xorK[ks]);
#pragma unroll
            for (int cf = 0; cf < 4; ++cf)
                b8[cf] = *(const long*)(B + bcOff + cf * 1024 + rdOff + xorK[ks]);
            __builtin_amdgcn_s_barrier();     // align all waves at MFMA entry
            asm volatile("s_waitcnt lgkmcnt(0)" ::: "memory");
            __builtin_amdgcn_sched_barrier(0);
            __builtin_amdgcn_s_setprio(1);
#pragma unroll
            for (int rf = 0; rf < 8; ++rf)
#pragma unroll
                for (int cf = 0; cf < 4; ++cf)
                    acc[rf][cf] = __builtin_amdgcn_mfma_f32_16x16x32_fp8_fp8(
                        a8[rf], b8[cf], acc[rf][cf], 0, 0, 0);
            __builtin_amdgcn_s_setprio(0);
            __builtin_amdgcn_s_barrier();     // all reads of buf[T&1] retired
        }
        if constexpr (T < 6) STAGE(T + 2);    // overwrites buf[T&1]: safe now
    };
    ktile(IC<0>{}); ktile(IC<1>{}); ktile(IC<2>{}); ktile(IC<3>{});
    ktile(IC<4>{}); ktile(IC<5>{}); ktile(IC<6>{}); ktile(IC<7>{});
#undef STAGE

    // ---- epilogue: row-side argmax (C/D: col=lane15+16*cf, row=quad*4+e) ----
    const int colLane = colBase + wc * 64 + lane15;
#pragma unroll
    for (int rf = 0; rf < 8; ++rf) {
#pragma unroll
        for (int e = 0; e < 4; ++e) {
            const int row = rowBase + wr * 128 + rf * 16 + quad * 4 + e;
            float bv = -3.0e38f;
            int   bc = 0;
#pragma unroll
            for (int cf = 0; cf < 4; ++cf) {
                const float v = acc[rf][cf][e];
                const int col = colLane + cf * 16;
                if (v > bv && col != row) { bv = v; bc = col; }
            }
            u64 packed = ((u64)fkey(bv) << 32) | (unsigned)(~bc);  // ~col: ties->lowest idx
#pragma unroll
            for (int m = 1; m < 16; m <<= 1) {
                u64 o = __shfl_xor(packed, m, 64);
                if (o > packed) packed = o;
            }
            if (lane15 == 0) atomicMax(&table[row], packed);
        }
    }

    // ---- epilogue: col-side (transposed) argmax for off-diagonal tiles ----
    if (rT != cT) {
#pragma unroll
        for (int cf = 0; cf < 4; ++cf) {
            const int col = colLane + cf * 16;
            float bv  = -3.0e38f;
            int   br_ = 0;
#pragma unroll
            for (int rf = 0; rf < 8; ++rf)
#pragma unroll
                for (int e = 0; e < 4; ++e) {
                    const float v = acc[rf][cf][e];
                    const int row = rowBase + wr * 128 + rf * 16 + quad * 4 + e;
                    if (v > bv) { bv = v; br_ = row; }
                }
            u64 packed = ((u64)fkey(bv) << 32) | (unsigned)(~br_);
            u64 o = __shfl_xor(packed, 16, 64); if (o > packed) packed = o;
            o     = __shfl_xor(packed, 32, 64); if (o > packed) packed = o;
            if (quad == 0) atomicMax(&table[col], packed);
        }
    }
}

// ---------------- kernel 3: rho + loss epilogue (fp32 exact) ----------------
__global__ __launch_bounds__(256)
void rho_loss_kernel(const float* __restrict__ x, const u64* __restrict__ table,
                     float* __restrict__ out) {
    const int lane = threadIdx.x & 63;
    const int wave = threadIdx.x >> 6;
    const int waveGlobal = blockIdx.x * 4 + wave;   // 2048 waves

    float local = 0.f;
    for (int r8 = 0; r8 < 8; ++r8) {
        const int row = waveGlobal * 8 + r8;
        const u64 packed = table[row];
        const int nb = (int)(~(unsigned)(packed & 0xFFFFFFFFu));

        const float4* xr = (const float4*)(x + (size_t)row * DIM);
        const float4* xn = (const float4*)(x + (size_t)nb  * DIM);
        float s = 0.f;
#pragma unroll
        for (int tt = 0; tt < 2; ++tt) {
            float4 a = xr[lane * 2 + tt];
            float4 b = xn[lane * 2 + tt];
            float d0 = a.x - b.x + 1e-6f;
            float d1 = a.y - b.y + 1e-6f;
            float d2 = a.z - b.z + 1e-6f;
            float d3 = a.w - b.w + 1e-6f;
            s += d0 * d0 + d1 * d1 + d2 * d2 + d3 * d3;
        }
#pragma unroll
        for (int m = 1; m < 64; m <<= 1) s += __shfl_xor(s, m, 64);

        if (lane == 0) {
            float rho = sqrtf(s);
            local += logf(rho + 1e-8f);
        }
    }
    if (lane == 0) atomicAdd(out, -local * (1.0f / 16384.0f));
}

extern "C" void kernel_launch(void* const* d_in, const int* in_sizes, int n_in,
                              void* d_out, int out_size, void* d_ws, size_t ws_size,
                              hipStream_t stream) {
    const float* x = (const float*)d_in[0];

    // Workspace: [0, 8 MiB) fp8 x; then 16384 x u64 argmax table.
    u8*    xb    = (u8*)d_ws;
    u64*   table = (u64*)((char*)d_ws + (size_t)N_ROWS * DIM);
    float* out   = (float*)d_out;

    hipMemsetAsync(out, 0, sizeof(float), stream);

    convert_fp8_kernel<<<2048, 256, 0, stream>>>(x, (unsigned*)xb, table);
    argmax_dots_kernel<<<2080, 512, 0, stream>>>(xb, table);
    rho_loss_kernel<<<512, 256, 0, stream>>>(x, table, out);
}